// Round 11
// baseline (237.196 us; speedup 1.0000x reference)
//
#include <hip/hip_runtime.h>
#include <hip/hip_bf16.h>
#include <math.h>

// SparseMLP: W=8 experts, per w: out = gelu(X @ W1 + b1) @ W2 + b2
// Round 11: R10 base (8-phase 256x256x64, 8 waves, frag ds_reads pipelined
// one phase ahead into ping-pong reg buffers, XOR-swizzled LDS via
// pre-swizzled gload source, expert->XCD pinning, X-convert prepass).
// NEW: ONE barrier per phase (8/iter instead of 16). The end-barrier's job
// is now done by:
//   (a) static audit: every PREFETCH_k region is disjoint from every
//       STAGES_{k+1} region in the same barrier interval (A vs B / cur vs
//       nxt for all 8 boundaries);
//   (b) counted vmcnt(4) moved to END of ph3/ph7 (BEFORE the next barrier),
//       so the barrier certifies ALL waves drained tile t+1 (resp t+2)
//       before any wave's PREFETCH reads it — a stronger cross-wave
//       guarantee than R10 (which read after only its own wave's vmcnt).
// Ledger (gload units of 1 instr, 2 per STAGE_xH): iter start B(t+1)[4];
// ph1 +A(t+1)h0[2]; ph2 +A(t+1)h1[2]+B(t+2)h0[2]; ph3 +B(t+2)h1[2] = 12
//   -> vmcnt(4) leaves B(t+2)[4], drains all of tile t+1; barrier; PF4 reads
//      nxt(t+1) safely.
// ph5 +A(t+2)h0[2]; ph6 +A(t+2)h1[2]+B(t+3)h0[2]; ph7 +B(t+3)h1[2] = 12
//   -> vmcnt(4) leaves B(t+3)[4]; barrier; PF8 reads cur(t+2) safely.

typedef float f32x4 __attribute__((ext_vector_type(4)));
typedef short bf16x8 __attribute__((ext_vector_type(8)));
typedef short bf16x4 __attribute__((ext_vector_type(4)));
typedef unsigned short u16;

#define NW 8
#define MDIM 2048   // BHS*SEQ
#define HDIM 2048
#define FFN  1024

static __device__ __forceinline__ u16 f32_to_bf16_rn(float f) {
  union { float f; unsigned u; } v; v.f = f;
  unsigned r = v.u + 0x7FFF + ((v.u >> 16) & 1);
  return (u16)(r >> 16);
}

static __device__ __forceinline__ void gload_lds16(const void* g, void* l) {
  __builtin_amdgcn_global_load_lds(
      (const __attribute__((address_space(1))) void*)g,
      (__attribute__((address_space(3))) void*)l, 16, 0, 0);
}

// X (NW*MDIM*HDIM f32) -> bf16 (4 f32/thread) + out_bias tail (last 16 blocks)
__global__ void convert_bf16_kernel(const float* __restrict__ in,
                                    u16* __restrict__ out,
                                    const float* __restrict__ b2,
                                    float* __restrict__ outb) {
  int bid = blockIdx.x;
  if (bid >= NW * MDIM * HDIM / 4 / 256) {  // bias tail
    int i = (bid - NW * MDIM * HDIM / 4 / 256) * 256 + threadIdx.x;
    if (i < NW * HDIM) outb[i] = b2[i];
    return;
  }
  size_t i = (size_t)bid * blockDim.x + threadIdx.x;  // f32x4 index
  f32x4 v = ((const f32x4*)in)[i];
  bf16x4 p;
  p[0] = (short)f32_to_bf16_rn(v.x);
  p[1] = (short)f32_to_bf16_rn(v.y);
  p[2] = (short)f32_to_bf16_rn(v.z);
  p[3] = (short)f32_to_bf16_rn(v.w);
  ((bf16x4*)out)[i] = p;
}

// in: (NW, R, C) f32 -> out: (NW, C, R) bf16 (convert + transpose), 64x64 tile
__global__ void convert_transpose_kernel(const float* __restrict__ in,
                                         u16* __restrict__ out, int R, int C) {
  __shared__ u16 tile[64][68];
  int w = blockIdx.z;
  int c0 = blockIdx.x * 64, r0 = blockIdx.y * 64;
  int t = threadIdx.x;  // 256 threads
  const float* ip = in + (size_t)w * R * C;
  u16* op = out + (size_t)w * C * R;
  int tr = t >> 4;       // 0..15
  int tc4 = (t & 15) * 4;
#pragma unroll
  for (int j = 0; j < 4; ++j) {
    int r = tr + j * 16;
    f32x4 v = *(const f32x4*)(ip + (size_t)(r0 + r) * C + c0 + tc4);
    tile[r][tc4 + 0] = f32_to_bf16_rn(v.x);
    tile[r][tc4 + 1] = f32_to_bf16_rn(v.y);
    tile[r][tc4 + 2] = f32_to_bf16_rn(v.z);
    tile[r][tc4 + 3] = f32_to_bf16_rn(v.w);
  }
  __syncthreads();
#pragma unroll
  for (int j = 0; j < 4; ++j) {
    int c = tr + j * 16;
    bf16x4 p;
    p[0] = (short)tile[tc4 + 0][c];
    p[1] = (short)tile[tc4 + 1][c];
    p[2] = (short)tile[tc4 + 2][c];
    p[3] = (short)tile[tc4 + 3][c];
    *(bf16x4*)(op + (size_t)(c0 + c) * R + r0 + tc4) = p;
  }
}

// ---------------- GEMM ----------------
// LDS layout per K-tile buffer (64KB): A0 @0, A1 @16384, B0 @32768, B1 @49152
#define STAGE_AH(dst, tt, h)                                                  \
  do {                                                                        \
    gload_lds16(gA + (size_t)(h) * 128 * rowK + (size_t)(tt) * 128,           \
                (dst) + (h) * 16384 + tid * 16);                              \
    gload_lds16(gA + ((size_t)(h) * 128 + 64) * rowK + (size_t)(tt) * 128,    \
                (dst) + (h) * 16384 + 8192 + tid * 16);                       \
  } while (0)
#define STAGE_BH(dst, tt, h)                                                  \
  do {                                                                        \
    gload_lds16(gB + (size_t)(h) * 128 * rowK + (size_t)(tt) * 128,           \
                (dst) + 32768 + (h) * 16384 + tid * 16);                      \
    gload_lds16(gB + ((size_t)(h) * 128 + 64) * rowK + (size_t)(tt) * 128,    \
                (dst) + 32768 + (h) * 16384 + 8192 + tid * 16);               \
  } while (0)

// fragment prefetch (into named ping-pong buffers; all indices static)
#define LOAD_A(DST, SB, q)                                                    \
  _Pragma("unroll") for (int ii = 0; ii < 2; ++ii)                            \
      _Pragma("unroll") for (int kk = 0; kk < 2; ++kk)                        \
          DST[ii][kk] = *(const bf16x8*)((SB) + Aoff +                        \
              ((q)*32 + ii * 16 + ra) * 128 + (colsw ^ (kk << 6)))
#define LOAD_B(DST, SB)                                                       \
  _Pragma("unroll") for (int jj = 0; jj < 4; ++jj)                            \
      _Pragma("unroll") for (int kk = 0; kk < 2; ++kk)                        \
          DST[jj][kk] = *(const bf16x8*)((SB) + Boff +                        \
              (brow + jj * 16 + ra) * 128 + (colsw ^ (kk << 6)))

// phase q (ONE barrier): {STAGES; barrier; lgkm; MFMA on preloaded AF/BF;
// VMCODE (counted vmcnt, ph3/ph7 only, BEFORE next barrier); PREFETCH}.
#define DO_PHASE(q, AF, BF, STAGES, VMCODE, PREFETCH)                         \
  {                                                                           \
    STAGES;                                                                   \
    __builtin_amdgcn_s_barrier();                                             \
    asm volatile("s_waitcnt lgkmcnt(0)" ::: "memory");                        \
    __builtin_amdgcn_sched_barrier(0);                                        \
    __builtin_amdgcn_s_setprio(1);                                            \
    _Pragma("unroll") for (int ii = 0; ii < 2; ++ii)                          \
        _Pragma("unroll") for (int jj = 0; jj < 4; ++jj)                      \
            _Pragma("unroll") for (int kk = 0; kk < 2; ++kk)                  \
                acc[(q)*2 + ii][jj] =                                         \
                    __builtin_amdgcn_mfma_f32_16x16x32_bf16(                  \
                        AF[ii][kk], BF[jj][kk], acc[(q)*2 + ii][jj],          \
                        0, 0, 0);                                             \
    __builtin_amdgcn_s_setprio(0);                                            \
    VMCODE;                                                                   \
    PREFETCH;                                                                 \
    __builtin_amdgcn_sched_barrier(0);                                        \
  }

template <bool GELU, bool C_F32>
__global__ __launch_bounds__(512, 2) void mlp_gemm(
    const u16* __restrict__ A, const u16* __restrict__ Bt,
    const float* __restrict__ bias, void* __restrict__ Cptr,
    int M, int N, int K, int nN) {
  __shared__ __align__(16) char lds[131072];
  char* cur = lds;
  char* nxt = lds + 65536;

  const int bid = blockIdx.x;
  const int w = bid & 7;            // expert -> pinned to XCD bid%8
  const int jb = bid >> 3;
  const int m0 = (jb / nN) * 256;
  const int n0 = (jb % nN) * 256;

  const int tid = threadIdx.x;
  const int wid = tid >> 6, lane = tid & 63;
  const int wr = wid >> 2, wc = wid & 3;   // 2 M-waves x 4 N-waves
  const int qa = lane >> 4, ra = lane & 15;

  const u16* ap = A + (size_t)w * M * K;
  const u16* btp = Bt + (size_t)w * N * K;
  const float* bp = bias + (size_t)w * N;

  const size_t rowK = (size_t)K * 2;
  const int r8 = tid >> 3;
  const int csw = ((tid & 7) * 16) ^ ((r8 & 7) << 4);
  const char* gA = (const char*)ap + (size_t)(m0 + r8) * rowK + csw;
  const char* gB = (const char*)btp + (size_t)(n0 + r8) * rowK + csw;

  const int colsw = (qa * 16) ^ ((ra & 7) << 4);
  const int Aoff = wr * 16384;
  const int Boff = 32768 + (wc >> 1) * 16384;
  const int brow = (wc & 1) * 64;

  f32x4 acc[8][4];
#pragma unroll
  for (int i = 0; i < 8; ++i)
#pragma unroll
    for (int j = 0; j < 4; ++j)
#pragma unroll
      for (int r = 0; r < 4; ++r) acc[i][j][r] = 0.0f;

  const int NT = K >> 6;        // even for both GEMMs
  const int nIter = NT >> 1;

  // prologue: tile0 (cur) fully + tile1 (nxt) B-halves; 12 loads/thread
  STAGE_BH(cur, 0, 0); STAGE_BH(cur, 0, 1);
  STAGE_AH(cur, 0, 0); STAGE_AH(cur, 0, 1);
  STAGE_BH(nxt, 1, 0); STAGE_BH(nxt, 1, 1);
  asm volatile("s_waitcnt vmcnt(4)" ::: "memory");  // tile0 landed; B(1) fly
  __builtin_amdgcn_sched_barrier(0);
  __builtin_amdgcn_s_barrier();

  bf16x8 afrA[2][2], afrB[2][2], bfrA[4][2], bfrB[4][2];
  // preload iter-0 ph1 fragments (tile0 resident)
  LOAD_B(bfrA, cur);
  LOAD_A(afrA, cur, 0);
  __builtin_amdgcn_sched_barrier(0);

  for (int it = 0; it < nIter; ++it) {
    const int t = it * 2;
    const bool s2 = (t + 2) < NT;   // NT even => (t+3)<NT iff s2

    // ---- K-tile t (cur) ----
    DO_PHASE(0, afrA, bfrA, { STAGE_AH(nxt, t + 1, 0); }, {},
             { LOAD_A(afrB, cur, 1); });
    DO_PHASE(1, afrB, bfrA,
             { STAGE_AH(nxt, t + 1, 1); if (s2) STAGE_BH(cur, t + 2, 0); }, {},
             { LOAD_A(afrA, cur, 2); });
    DO_PHASE(2, afrA, bfrA, { if (s2) STAGE_BH(cur, t + 2, 1); }, {
      if (s2) asm volatile("s_waitcnt vmcnt(4)" ::: "memory");
      else    asm volatile("s_waitcnt vmcnt(0)" ::: "memory");
      __builtin_amdgcn_sched_barrier(0);   // tile t+1 drained before ph4's B
    }, { LOAD_A(afrB, cur, 3); });
    DO_PHASE(3, afrB, bfrA, {}, {},
             { LOAD_B(bfrB, nxt); LOAD_A(afrA, nxt, 0); });  // t+1 safe (B4)

    // ---- K-tile t+1 (nxt) ----
    DO_PHASE(0, afrA, bfrB, { if (s2) STAGE_AH(cur, t + 2, 0); }, {},
             { LOAD_A(afrB, nxt, 1); });
    DO_PHASE(1, afrB, bfrB,
             { if (s2) { STAGE_AH(cur, t + 2, 1); STAGE_BH(nxt, t + 3, 0); } }, {},
             { LOAD_A(afrA, nxt, 2); });
    DO_PHASE(2, afrA, bfrB, { if (s2) STAGE_BH(nxt, t + 3, 1); }, {
      if (s2) asm volatile("s_waitcnt vmcnt(4)" ::: "memory");
      else    asm volatile("s_waitcnt vmcnt(0)" ::: "memory");
      __builtin_amdgcn_sched_barrier(0);   // tile t+2 drained before ph8's B
    }, { LOAD_A(afrB, nxt, 3); });
    DO_PHASE(3, afrB, bfrB, {}, {},
             { LOAD_B(bfrA, cur); LOAD_A(afrA, cur, 0); });  // t+2 safe (B8)
    // (last iter: final prefetch reads stale LDS; values never consumed)
  }

  // epilogue: + bias, optional exact GELU, store
#pragma unroll
  for (int i = 0; i < 8; ++i) {
#pragma unroll
    for (int j = 0; j < 4; ++j) {
      int col = n0 + wc * 64 + j * 16 + ra;
      float bv = bp[col];
#pragma unroll
      for (int r = 0; r < 4; ++r) {
        int row = m0 + wr * 128 + i * 16 + qa * 4 + r;
        float v = acc[i][j][r] + bv;
        if (GELU) v = 0.5f * v * (1.0f + erff(v * 0.70710678118654752f));
        if (C_F32)
          ((float*)Cptr)[(size_t)w * M * N + (size_t)row * N + col] = v;
        else
          ((u16*)Cptr)[(size_t)w * M * N + (size_t)row * N + col] =
              f32_to_bf16_rn(v);
      }
    }
  }
}

extern "C" void kernel_launch(void* const* d_in, const int* in_sizes, int n_in,
                              void* d_out, int out_size, void* d_ws,
                              size_t ws_size, hipStream_t stream) {
  const float* hs = (const float*)d_in[0];  // (8,2,1024,2048) f32
  const float* w1 = (const float*)d_in[1];  // (8,2048,1024) f32
  const float* b1 = (const float*)d_in[2];  // (8,1,1024) f32
  const float* w2 = (const float*)d_in[3];  // (8,1024,2048) f32
  const float* b2 = (const float*)d_in[4];  // (8,2048) f32

  // ws (u16): W1t (8,1024,2048) | W2t (8,2048,1024) | inter (8,2048,1024) | Xb
  u16* W1t = (u16*)d_ws;
  u16* W2t = W1t + (size_t)NW * FFN * HDIM;
  u16* inter = W2t + (size_t)NW * HDIM * FFN;
  u16* XbWs = inter + (size_t)NW * MDIM * FFN;
  size_t need = ((size_t)NW * FFN * HDIM * 2 + (size_t)NW * MDIM * FFN +
                 (size_t)NW * MDIM * HDIM) * sizeof(u16);
  u16* Xb = (ws_size >= need) ? XbWs : (u16*)d_out;

  float* outb = (float*)d_out + (size_t)NW * MDIM * HDIM;

  // X -> bf16 (+ bias tail in the same dispatch)
  convert_bf16_kernel<<<dim3(NW * MDIM * HDIM / 4 / 256 + 16), 256, 0,
                        stream>>>(hs, Xb, b2, outb);
  // w1 (R=HDIM, C=FFN) -> W1t (FFN, HDIM)
  convert_transpose_kernel<<<dim3(FFN / 64, HDIM / 64, NW), 256, 0, stream>>>(
      w1, W1t, HDIM, FFN);
  // w2 (R=FFN, C=HDIM) -> W2t (HDIM, FFN)
  convert_transpose_kernel<<<dim3(HDIM / 64, FFN / 64, NW), 256, 0, stream>>>(
      w2, W2t, FFN, HDIM);

  // inter = gelu(X @ W1 + b1)  [bf16]  M=2048 N=1024 K=2048 -> 256 blocks
  mlp_gemm<true, false>
      <<<dim3(NW * (MDIM / 256) * (FFN / 256)), 512, 0, stream>>>(
          Xb, W1t, b1, inter, MDIM, FFN, HDIM, FFN / 256);
  // out = inter @ W2 + b2  [f32]  M=2048 N=2048 K=1024 -> 512 blocks
  mlp_gemm<false, true>
      <<<dim3(NW * (MDIM / 256) * (HDIM / 256)), 512, 0, stream>>>(
          inter, W2t, b2, d_out, MDIM, HDIM, FFN, HDIM / 256);
}

// Round 12
// 233.570 us; speedup vs baseline: 1.0155x; 1.0155x over previous
//
#include <hip/hip_runtime.h>
#include <hip/hip_bf16.h>
#include <math.h>

// SparseMLP: W=8 experts, per w: out = gelu(X @ W1 + b1) @ W2 + b2
// Round 12: minimal-sync GEMM. Same geometry as R10/R11 (256x256x64, 8 waves
// 2Mx4N, 128KB LDS = full 2-K-tile double buffer, XOR-swizzled LDS via
// pre-swizzled gload source, expert->XCD pinning, frag ds_reads pipelined
// into ping-pong reg buffers). NEW: ONE barrier + ONE vmcnt per K-tile
// (vs 4+2 in R11). Made legal by staging only 1 tile ahead:
//   iter t: reads hit cur ONLY; all 8 stage gloads (A+B of t+1) target nxt
//   ONLY -> zero intra-tile WAR. vmcnt(0) at iter end drains exactly the 8
//   just-issued loads (in flight a full K-tile ~2500cyc >> 900cyc HBM);
//   barrier certifies all waves drained before any wave's post-barrier
//   prefetch reads nxt. B-frags of tile t live in regs all tile (single
//   bfr buffer, loaded post-barrier) -> frag VGPR 96->64.
// sched_barrier(0) right after s_barrier prevents the compiler hoisting the
// nxt-frag ds_reads above the barrier (raw s_barrier is not an LLVM fence).

typedef float f32x4 __attribute__((ext_vector_type(4)));
typedef short bf16x8 __attribute__((ext_vector_type(8)));
typedef short bf16x4 __attribute__((ext_vector_type(4)));
typedef unsigned short u16;

#define NW 8
#define MDIM 2048   // BHS*SEQ
#define HDIM 2048
#define FFN  1024

static __device__ __forceinline__ u16 f32_to_bf16_rn(float f) {
  union { float f; unsigned u; } v; v.f = f;
  unsigned r = v.u + 0x7FFF + ((v.u >> 16) & 1);
  return (u16)(r >> 16);
}

static __device__ __forceinline__ void gload_lds16(const void* g, void* l) {
  __builtin_amdgcn_global_load_lds(
      (const __attribute__((address_space(1))) void*)g,
      (__attribute__((address_space(3))) void*)l, 16, 0, 0);
}

// X (NW*MDIM*HDIM f32) -> bf16 (4 f32/thread) + out_bias tail (last 16 blocks)
__global__ void convert_bf16_kernel(const float* __restrict__ in,
                                    u16* __restrict__ out,
                                    const float* __restrict__ b2,
                                    float* __restrict__ outb) {
  int bid = blockIdx.x;
  if (bid >= NW * MDIM * HDIM / 4 / 256) {  // bias tail
    int i = (bid - NW * MDIM * HDIM / 4 / 256) * 256 + threadIdx.x;
    if (i < NW * HDIM) outb[i] = b2[i];
    return;
  }
  size_t i = (size_t)bid * blockDim.x + threadIdx.x;  // f32x4 index
  f32x4 v = ((const f32x4*)in)[i];
  bf16x4 p;
  p[0] = (short)f32_to_bf16_rn(v.x);
  p[1] = (short)f32_to_bf16_rn(v.y);
  p[2] = (short)f32_to_bf16_rn(v.z);
  p[3] = (short)f32_to_bf16_rn(v.w);
  ((bf16x4*)out)[i] = p;
}

// in: (NW, R, C) f32 -> out: (NW, C, R) bf16 (convert + transpose), 64x64 tile
__global__ void convert_transpose_kernel(const float* __restrict__ in,
                                         u16* __restrict__ out, int R, int C) {
  __shared__ u16 tile[64][68];
  int w = blockIdx.z;
  int c0 = blockIdx.x * 64, r0 = blockIdx.y * 64;
  int t = threadIdx.x;  // 256 threads
  const float* ip = in + (size_t)w * R * C;
  u16* op = out + (size_t)w * C * R;
  int tr = t >> 4;       // 0..15
  int tc4 = (t & 15) * 4;
#pragma unroll
  for (int j = 0; j < 4; ++j) {
    int r = tr + j * 16;
    f32x4 v = *(const f32x4*)(ip + (size_t)(r0 + r) * C + c0 + tc4);
    tile[r][tc4 + 0] = f32_to_bf16_rn(v.x);
    tile[r][tc4 + 1] = f32_to_bf16_rn(v.y);
    tile[r][tc4 + 2] = f32_to_bf16_rn(v.z);
    tile[r][tc4 + 3] = f32_to_bf16_rn(v.w);
  }
  __syncthreads();
#pragma unroll
  for (int j = 0; j < 4; ++j) {
    int c = tr + j * 16;
    bf16x4 p;
    p[0] = (short)tile[tc4 + 0][c];
    p[1] = (short)tile[tc4 + 1][c];
    p[2] = (short)tile[tc4 + 2][c];
    p[3] = (short)tile[tc4 + 3][c];
    *(bf16x4*)(op + (size_t)(c0 + c) * R + r0 + tc4) = p;
  }
}

// ---------------- GEMM ----------------
// LDS layout per K-tile buffer (64KB): A0 @0, A1 @16384, B0 @32768, B1 @49152
#define STAGE_AH(dst, tt, h)                                                  \
  do {                                                                        \
    gload_lds16(gA + (size_t)(h) * 128 * rowK + (size_t)(tt) * 128,           \
                (dst) + (h) * 16384 + tid * 16);                              \
    gload_lds16(gA + ((size_t)(h) * 128 + 64) * rowK + (size_t)(tt) * 128,    \
                (dst) + (h) * 16384 + 8192 + tid * 16);                       \
  } while (0)
#define STAGE_BH(dst, tt, h)                                                  \
  do {                                                                        \
    gload_lds16(gB + (size_t)(h) * 128 * rowK + (size_t)(tt) * 128,           \
                (dst) + 32768 + (h) * 16384 + tid * 16);                      \
    gload_lds16(gB + ((size_t)(h) * 128 + 64) * rowK + (size_t)(tt) * 128,    \
                (dst) + 32768 + (h) * 16384 + 8192 + tid * 16);               \
  } while (0)

// fragment loads (into named buffers; all indices static)
#define LOAD_A(DST, SB, q)                                                    \
  _Pragma("unroll") for (int ii = 0; ii < 2; ++ii)                            \
      _Pragma("unroll") for (int kk = 0; kk < 2; ++kk)                        \
          DST[ii][kk] = *(const bf16x8*)((SB) + Aoff +                        \
              ((q)*32 + ii * 16 + ra) * 128 + (colsw ^ (kk << 6)))
#define LOAD_B(DST, SB)                                                       \
  _Pragma("unroll") for (int jj = 0; jj < 4; ++jj)                            \
      _Pragma("unroll") for (int kk = 0; kk < 2; ++kk)                        \
          DST[jj][kk] = *(const bf16x8*)((SB) + Boff +                        \
              (brow + jj * 16 + ra) * 128 + (colsw ^ (kk << 6)))

// 16-MFMA cluster for C-quadrant q using A-frags AF (B-frags in bfr)
#define MFMA_Q(q, AF)                                                         \
  {                                                                           \
    __builtin_amdgcn_s_setprio(1);                                            \
    _Pragma("unroll") for (int ii = 0; ii < 2; ++ii)                          \
        _Pragma("unroll") for (int jj = 0; jj < 4; ++jj)                      \
            _Pragma("unroll") for (int kk = 0; kk < 2; ++kk)                  \
                acc[(q)*2 + ii][jj] =                                         \
                    __builtin_amdgcn_mfma_f32_16x16x32_bf16(                  \
                        AF[ii][kk], bfr[jj][kk], acc[(q)*2 + ii][jj],         \
                        0, 0, 0);                                             \
    __builtin_amdgcn_s_setprio(0);                                            \
  }

template <bool GELU, bool C_F32>
__global__ __launch_bounds__(512, 2) void mlp_gemm(
    const u16* __restrict__ A, const u16* __restrict__ Bt,
    const float* __restrict__ bias, void* __restrict__ Cptr,
    int M, int N, int K, int nN) {
  __shared__ __align__(16) char lds[131072];
  char* cur = lds;
  char* nxt = lds + 65536;

  const int bid = blockIdx.x;
  const int w = bid & 7;            // expert -> pinned to XCD bid%8
  const int jb = bid >> 3;
  const int m0 = (jb / nN) * 256;
  const int n0 = (jb % nN) * 256;

  const int tid = threadIdx.x;
  const int wid = tid >> 6, lane = tid & 63;
  const int wr = wid >> 2, wc = wid & 3;   // 2 M-waves x 4 N-waves
  const int qa = lane >> 4, ra = lane & 15;

  const u16* ap = A + (size_t)w * M * K;
  const u16* btp = Bt + (size_t)w * N * K;
  const float* bp = bias + (size_t)w * N;

  const size_t rowK = (size_t)K * 2;
  const int r8 = tid >> 3;
  const int csw = ((tid & 7) * 16) ^ ((r8 & 7) << 4);
  const char* gA = (const char*)ap + (size_t)(m0 + r8) * rowK + csw;
  const char* gB = (const char*)btp + (size_t)(n0 + r8) * rowK + csw;

  const int colsw = (qa * 16) ^ ((ra & 7) << 4);
  const int Aoff = wr * 16384;
  const int Boff = 32768 + (wc >> 1) * 16384;
  const int brow = (wc & 1) * 64;

  f32x4 acc[8][4];
#pragma unroll
  for (int i = 0; i < 8; ++i)
#pragma unroll
    for (int j = 0; j < 4; ++j)
#pragma unroll
      for (int r = 0; r < 4; ++r) acc[i][j][r] = 0.0f;

  const int NT = K >> 6;

  // prologue: stage tile 0 -> cur; wait; preload its B-frags + A-q0 frags
  STAGE_AH(cur, 0, 0); STAGE_AH(cur, 0, 1);
  STAGE_BH(cur, 0, 0); STAGE_BH(cur, 0, 1);
  asm volatile("s_waitcnt vmcnt(0)" ::: "memory");
  __builtin_amdgcn_s_barrier();
  __builtin_amdgcn_sched_barrier(0);

  bf16x8 bfr[4][2], afrA[2][2], afrB[2][2];
  LOAD_B(bfr, cur);
  LOAD_A(afrA, cur, 0);

  for (int t = 0; t < NT; ++t) {
    const bool pf = (t + 1) < NT;
    // stage next tile (8 gloads), issued before compute
    if (pf) {
      STAGE_AH(nxt, t + 1, 0); STAGE_AH(nxt, t + 1, 1);
      STAGE_BH(nxt, t + 1, 0); STAGE_BH(nxt, t + 1, 1);
    }
    __builtin_amdgcn_sched_barrier(0);   // pin stage-issue before compute

    // interleave: prefetch next quadrant's A-frags between MFMA clusters
    LOAD_A(afrB, cur, 1);
    MFMA_Q(0, afrA);
    LOAD_A(afrA, cur, 2);
    MFMA_Q(1, afrB);
    LOAD_A(afrB, cur, 3);
    MFMA_Q(2, afrA);
    MFMA_Q(3, afrB);

    // single sync point per K-tile
    asm volatile("s_waitcnt vmcnt(0)" ::: "memory");  // t+1's 8 loads landed
    __builtin_amdgcn_s_barrier();
    __builtin_amdgcn_sched_barrier(0);   // nothing hoists above the barrier

    if (pf) {
      LOAD_B(bfr, nxt);
      LOAD_A(afrA, nxt, 0);
    }
    char* tp = cur; cur = nxt; nxt = tp;
  }

  // epilogue: + bias, optional exact GELU, store
#pragma unroll
  for (int i = 0; i < 8; ++i) {
#pragma unroll
    for (int j = 0; j < 4; ++j) {
      int col = n0 + wc * 64 + j * 16 + ra;
      float bv = bp[col];
#pragma unroll
      for (int r = 0; r < 4; ++r) {
        int row = m0 + wr * 128 + i * 16 + qa * 4 + r;
        float v = acc[i][j][r] + bv;
        if (GELU) v = 0.5f * v * (1.0f + erff(v * 0.70710678118654752f));
        if (C_F32)
          ((float*)Cptr)[(size_t)w * M * N + (size_t)row * N + col] = v;
        else
          ((u16*)Cptr)[(size_t)w * M * N + (size_t)row * N + col] =
              f32_to_bf16_rn(v);
      }
    }
  }
}

extern "C" void kernel_launch(void* const* d_in, const int* in_sizes, int n_in,
                              void* d_out, int out_size, void* d_ws,
                              size_t ws_size, hipStream_t stream) {
  const float* hs = (const float*)d_in[0];  // (8,2,1024,2048) f32
  const float* w1 = (const float*)d_in[1];  // (8,2048,1024) f32
  const float* b1 = (const float*)d_in[2];  // (8,1,1024) f32
  const float* w2 = (const float*)d_in[3];  // (8,1024,2048) f32
  const float* b2 = (const float*)d_in[4];  // (8,2048) f32

  // ws (u16): W1t (8,1024,2048) | W2t (8,2048,1024) | inter (8,2048,1024) | Xb
  u16* W1t = (u16*)d_ws;
  u16* W2t = W1t + (size_t)NW * FFN * HDIM;
  u16* inter = W2t + (size_t)NW * HDIM * FFN;
  u16* XbWs = inter + (size_t)NW * MDIM * FFN;
  size_t need = ((size_t)NW * FFN * HDIM * 2 + (size_t)NW * MDIM * FFN +
                 (size_t)NW * MDIM * HDIM) * sizeof(u16);
  u16* Xb = (ws_size >= need) ? XbWs : (u16*)d_out;

  float* outb = (float*)d_out + (size_t)NW * MDIM * HDIM;

  // X -> bf16 (+ bias tail in the same dispatch)
  convert_bf16_kernel<<<dim3(NW * MDIM * HDIM / 4 / 256 + 16), 256, 0,
                        stream>>>(hs, Xb, b2, outb);
  // w1 (R=HDIM, C=FFN) -> W1t (FFN, HDIM)
  convert_transpose_kernel<<<dim3(FFN / 64, HDIM / 64, NW), 256, 0, stream>>>(
      w1, W1t, HDIM, FFN);
  // w2 (R=FFN, C=HDIM) -> W2t (HDIM, FFN)
  convert_transpose_kernel<<<dim3(HDIM / 64, FFN / 64, NW), 256, 0, stream>>>(
      w2, W2t, FFN, HDIM);

  // inter = gelu(X @ W1 + b1)  [bf16]  M=2048 N=1024 K=2048 -> 256 blocks
  mlp_gemm<true, false>
      <<<dim3(NW * (MDIM / 256) * (FFN / 256)), 512, 0, stream>>>(
          Xb, W1t, b1, inter, MDIM, FFN, HDIM, FFN / 256);
  // out = inter @ W2 + b2  [f32]  M=2048 N=2048 K=1024 -> 512 blocks
  mlp_gemm<false, true>
      <<<dim3(NW * (MDIM / 256) * (HDIM / 256)), 512, 0, stream>>>(
          inter, W2t, b2, d_out, MDIM, HDIM, FFN, HDIM / 256);
}

// Round 13
// 227.152 us; speedup vs baseline: 1.0442x; 1.0283x over previous
//
#include <hip/hip_runtime.h>
#include <hip/hip_bf16.h>
#include <math.h>

// SparseMLP: W=8 experts, per w: out = gelu(X @ W1 + b1) @ W2 + b2
// Round 13: R12 GEMMs verbatim (256x256x64, 8 waves, 1 barrier + 1 vmcnt per
// K-tile, frag ping-pong prefetch, XOR-swizzled LDS via pre-swizzled gload
// source, expert->XCD pinning). NEW: ALL prep fused into ONE dispatch --
// per-block bodies are VERBATIM copies of the proven convert / transpose /
// bias kernels (only grid indexing changed; R7's fused-prep regression came
// from a rewritten body, not fusion). Saves 2 launches + overlaps tails.
// Grid sections: [0, 4096) w1^T | [4096, 8192) w2^T | [8192, 40960) X-cvt |
// [40960, 40976) bias tail.

typedef float f32x4 __attribute__((ext_vector_type(4)));
typedef short bf16x8 __attribute__((ext_vector_type(8)));
typedef short bf16x4 __attribute__((ext_vector_type(4)));
typedef unsigned short u16;

#define NW 8
#define MDIM 2048   // BHS*SEQ
#define HDIM 2048
#define FFN  1024

static __device__ __forceinline__ u16 f32_to_bf16_rn(float f) {
  union { float f; unsigned u; } v; v.f = f;
  unsigned r = v.u + 0x7FFF + ((v.u >> 16) & 1);
  return (u16)(r >> 16);
}

static __device__ __forceinline__ void gload_lds16(const void* g, void* l) {
  __builtin_amdgcn_global_load_lds(
      (const __attribute__((address_space(1))) void*)g,
      (__attribute__((address_space(3))) void*)l, 16, 0, 0);
}

// ---------------- fused prep ----------------
// body verbatim from convert_transpose_kernel (R4..R12)
static __device__ __forceinline__ void transpose_body(
    const float* __restrict__ in, u16* __restrict__ out, int R, int C,
    int bx, int by, int bz, u16 (*tile)[68]) {
  int w = bz;
  int c0 = bx * 64, r0 = by * 64;
  int t = threadIdx.x;  // 256 threads
  const float* ip = in + (size_t)w * R * C;
  u16* op = out + (size_t)w * C * R;
  int tr = t >> 4;       // 0..15
  int tc4 = (t & 15) * 4;
#pragma unroll
  for (int j = 0; j < 4; ++j) {
    int r = tr + j * 16;
    f32x4 v = *(const f32x4*)(ip + (size_t)(r0 + r) * C + c0 + tc4);
    tile[r][tc4 + 0] = f32_to_bf16_rn(v.x);
    tile[r][tc4 + 1] = f32_to_bf16_rn(v.y);
    tile[r][tc4 + 2] = f32_to_bf16_rn(v.z);
    tile[r][tc4 + 3] = f32_to_bf16_rn(v.w);
  }
  __syncthreads();
#pragma unroll
  for (int j = 0; j < 4; ++j) {
    int c = tr + j * 16;
    bf16x4 p;
    p[0] = (short)tile[tc4 + 0][c];
    p[1] = (short)tile[tc4 + 1][c];
    p[2] = (short)tile[tc4 + 2][c];
    p[3] = (short)tile[tc4 + 3][c];
    *(bf16x4*)(op + (size_t)(c0 + c) * R + r0 + tc4) = p;
  }
}

#define NB_T1 4096   // (FFN/64) x (HDIM/64) x NW = 16*32*8
#define NB_T2 4096   // (HDIM/64) x (FFN/64) x NW = 32*16*8
#define NB_CV 32768  // NW*MDIM*HDIM/4/256

__global__ void prep_kernel(const float* __restrict__ hs,
                            const float* __restrict__ w1,
                            const float* __restrict__ w2,
                            const float* __restrict__ b2,
                            u16* __restrict__ Xb, u16* __restrict__ W1t,
                            u16* __restrict__ W2t, float* __restrict__ outb) {
  __shared__ u16 tile[64][68];
  int bid = blockIdx.x;
  if (bid < NB_T1) {  // w1 (R=HDIM,C=FFN) -> W1t ; grid was (16,32,8)
    transpose_body(w1, W1t, HDIM, FFN, bid % 16, (bid / 16) % 32, bid / 512,
                   tile);
    return;
  }
  bid -= NB_T1;
  if (bid < NB_T2) {  // w2 (R=FFN,C=HDIM) -> W2t ; grid was (32,16,8)
    transpose_body(w2, W2t, FFN, HDIM, bid % 32, (bid / 32) % 16, bid / 512,
                   tile);
    return;
  }
  bid -= NB_T2;
  if (bid < NB_CV) {  // X -> bf16, body verbatim from convert_bf16_kernel
    size_t i = (size_t)bid * blockDim.x + threadIdx.x;  // f32x4 index
    f32x4 v = ((const f32x4*)hs)[i];
    bf16x4 p;
    p[0] = (short)f32_to_bf16_rn(v.x);
    p[1] = (short)f32_to_bf16_rn(v.y);
    p[2] = (short)f32_to_bf16_rn(v.z);
    p[3] = (short)f32_to_bf16_rn(v.w);
    ((bf16x4*)Xb)[i] = p;
    return;
  }
  bid -= NB_CV;
  {  // bias tail
    int i = bid * 256 + threadIdx.x;
    if (i < NW * HDIM) outb[i] = b2[i];
  }
}

// ---------------- GEMM (R12 verbatim) ----------------
// LDS layout per K-tile buffer (64KB): A0 @0, A1 @16384, B0 @32768, B1 @49152
#define STAGE_AH(dst, tt, h)                                                  \
  do {                                                                        \
    gload_lds16(gA + (size_t)(h) * 128 * rowK + (size_t)(tt) * 128,           \
                (dst) + (h) * 16384 + tid * 16);                              \
    gload_lds16(gA + ((size_t)(h) * 128 + 64) * rowK + (size_t)(tt) * 128,    \
                (dst) + (h) * 16384 + 8192 + tid * 16);                       \
  } while (0)
#define STAGE_BH(dst, tt, h)                                                  \
  do {                                                                        \
    gload_lds16(gB + (size_t)(h) * 128 * rowK + (size_t)(tt) * 128,           \
                (dst) + 32768 + (h) * 16384 + tid * 16);                      \
    gload_lds16(gB + ((size_t)(h) * 128 + 64) * rowK + (size_t)(tt) * 128,    \
                (dst) + 32768 + (h) * 16384 + 8192 + tid * 16);               \
  } while (0)

#define LOAD_A(DST, SB, q)                                                    \
  _Pragma("unroll") for (int ii = 0; ii < 2; ++ii)                            \
      _Pragma("unroll") for (int kk = 0; kk < 2; ++kk)                        \
          DST[ii][kk] = *(const bf16x8*)((SB) + Aoff +                        \
              ((q)*32 + ii * 16 + ra) * 128 + (colsw ^ (kk << 6)))
#define LOAD_B(DST, SB)                                                       \
  _Pragma("unroll") for (int jj = 0; jj < 4; ++jj)                            \
      _Pragma("unroll") for (int kk = 0; kk < 2; ++kk)                        \
          DST[jj][kk] = *(const bf16x8*)((SB) + Boff +                        \
              (brow + jj * 16 + ra) * 128 + (colsw ^ (kk << 6)))

#define MFMA_Q(q, AF)                                                         \
  {                                                                           \
    __builtin_amdgcn_s_setprio(1);                                            \
    _Pragma("unroll") for (int ii = 0; ii < 2; ++ii)                          \
        _Pragma("unroll") for (int jj = 0; jj < 4; ++jj)                      \
            _Pragma("unroll") for (int kk = 0; kk < 2; ++kk)                  \
                acc[(q)*2 + ii][jj] =                                         \
                    __builtin_amdgcn_mfma_f32_16x16x32_bf16(                  \
                        AF[ii][kk], bfr[jj][kk], acc[(q)*2 + ii][jj],         \
                        0, 0, 0);                                             \
    __builtin_amdgcn_s_setprio(0);                                            \
  }

template <bool GELU, bool C_F32>
__global__ __launch_bounds__(512, 2) void mlp_gemm(
    const u16* __restrict__ A, const u16* __restrict__ Bt,
    const float* __restrict__ bias, void* __restrict__ Cptr,
    int M, int N, int K, int nN) {
  __shared__ __align__(16) char lds[131072];
  char* cur = lds;
  char* nxt = lds + 65536;

  const int bid = blockIdx.x;
  const int w = bid & 7;            // expert -> pinned to XCD bid%8
  const int jb = bid >> 3;
  const int m0 = (jb / nN) * 256;
  const int n0 = (jb % nN) * 256;

  const int tid = threadIdx.x;
  const int wid = tid >> 6, lane = tid & 63;
  const int wr = wid >> 2, wc = wid & 3;   // 2 M-waves x 4 N-waves
  const int qa = lane >> 4, ra = lane & 15;

  const u16* ap = A + (size_t)w * M * K;
  const u16* btp = Bt + (size_t)w * N * K;
  const float* bp = bias + (size_t)w * N;

  const size_t rowK = (size_t)K * 2;
  const int r8 = tid >> 3;
  const int csw = ((tid & 7) * 16) ^ ((r8 & 7) << 4);
  const char* gA = (const char*)ap + (size_t)(m0 + r8) * rowK + csw;
  const char* gB = (const char*)btp + (size_t)(n0 + r8) * rowK + csw;

  const int colsw = (qa * 16) ^ ((ra & 7) << 4);
  const int Aoff = wr * 16384;
  const int Boff = 32768 + (wc >> 1) * 16384;
  const int brow = (wc & 1) * 64;

  f32x4 acc[8][4];
#pragma unroll
  for (int i = 0; i < 8; ++i)
#pragma unroll
    for (int j = 0; j < 4; ++j)
#pragma unroll
      for (int r = 0; r < 4; ++r) acc[i][j][r] = 0.0f;

  const int NT = K >> 6;

  // prologue: stage tile 0 -> cur; wait; preload its B-frags + A-q0 frags
  STAGE_AH(cur, 0, 0); STAGE_AH(cur, 0, 1);
  STAGE_BH(cur, 0, 0); STAGE_BH(cur, 0, 1);
  asm volatile("s_waitcnt vmcnt(0)" ::: "memory");
  __builtin_amdgcn_s_barrier();
  __builtin_amdgcn_sched_barrier(0);

  bf16x8 bfr[4][2], afrA[2][2], afrB[2][2];
  LOAD_B(bfr, cur);
  LOAD_A(afrA, cur, 0);

  for (int t = 0; t < NT; ++t) {
    const bool pf = (t + 1) < NT;
    if (pf) {
      STAGE_AH(nxt, t + 1, 0); STAGE_AH(nxt, t + 1, 1);
      STAGE_BH(nxt, t + 1, 0); STAGE_BH(nxt, t + 1, 1);
    }
    __builtin_amdgcn_sched_barrier(0);   // pin stage-issue before compute

    LOAD_A(afrB, cur, 1);
    MFMA_Q(0, afrA);
    LOAD_A(afrA, cur, 2);
    MFMA_Q(1, afrB);
    LOAD_A(afrB, cur, 3);
    MFMA_Q(2, afrA);
    MFMA_Q(3, afrB);

    asm volatile("s_waitcnt vmcnt(0)" ::: "memory");  // t+1's 8 loads landed
    __builtin_amdgcn_s_barrier();
    __builtin_amdgcn_sched_barrier(0);   // nothing hoists above the barrier

    if (pf) {
      LOAD_B(bfr, nxt);
      LOAD_A(afrA, nxt, 0);
    }
    char* tp = cur; cur = nxt; nxt = tp;
  }

  // epilogue: + bias, optional exact GELU, store
#pragma unroll
  for (int i = 0; i < 8; ++i) {
#pragma unroll
    for (int j = 0; j < 4; ++j) {
      int col = n0 + wc * 64 + j * 16 + ra;
      float bv = bp[col];
#pragma unroll
      for (int r = 0; r < 4; ++r) {
        int row = m0 + wr * 128 + i * 16 + qa * 4 + r;
        float v = acc[i][j][r] + bv;
        if (GELU) v = 0.5f * v * (1.0f + erff(v * 0.70710678118654752f));
        if (C_F32)
          ((float*)Cptr)[(size_t)w * M * N + (size_t)row * N + col] = v;
        else
          ((u16*)Cptr)[(size_t)w * M * N + (size_t)row * N + col] =
              f32_to_bf16_rn(v);
      }
    }
  }
}

extern "C" void kernel_launch(void* const* d_in, const int* in_sizes, int n_in,
                              void* d_out, int out_size, void* d_ws,
                              size_t ws_size, hipStream_t stream) {
  const float* hs = (const float*)d_in[0];  // (8,2,1024,2048) f32
  const float* w1 = (const float*)d_in[1];  // (8,2048,1024) f32
  const float* b1 = (const float*)d_in[2];  // (8,1,1024) f32
  const float* w2 = (const float*)d_in[3];  // (8,1024,2048) f32
  const float* b2 = (const float*)d_in[4];  // (8,2048) f32

  // ws (u16): W1t (8,1024,2048) | W2t (8,2048,1024) | inter (8,2048,1024) | Xb
  u16* W1t = (u16*)d_ws;
  u16* W2t = W1t + (size_t)NW * FFN * HDIM;
  u16* inter = W2t + (size_t)NW * HDIM * FFN;
  u16* XbWs = inter + (size_t)NW * MDIM * FFN;
  size_t need = ((size_t)NW * FFN * HDIM * 2 + (size_t)NW * MDIM * FFN +
                 (size_t)NW * MDIM * HDIM) * sizeof(u16);
  u16* Xb = (ws_size >= need) ? XbWs : (u16*)d_out;

  float* outb = (float*)d_out + (size_t)NW * MDIM * HDIM;

  // single fused prep dispatch: w1^T | w2^T | X->bf16 | bias tail
  prep_kernel<<<dim3(NB_T1 + NB_T2 + NB_CV + 16), 256, 0, stream>>>(
      hs, w1, w2, b2, Xb, W1t, W2t, outb);

  // inter = gelu(X @ W1 + b1)  [bf16]  M=2048 N=1024 K=2048 -> 256 blocks
  mlp_gemm<true, false>
      <<<dim3(NW * (MDIM / 256) * (FFN / 256)), 512, 0, stream>>>(
          Xb, W1t, b1, inter, MDIM, FFN, HDIM, FFN / 256);
  // out = inter @ W2 + b2  [f32]  M=2048 N=2048 K=1024 -> 512 blocks
  mlp_gemm<false, true>
      <<<dim3(NW * (MDIM / 256) * (HDIM / 256)), 512, 0, stream>>>(
          inter, W2t, b2, d_out, MDIM, HDIM, FFN, HDIM / 256);
}